// Round 6
// baseline (591.103 us; speedup 1.0000x reference)
//
#include <hip/hip_runtime.h>
#include <math.h>

#define NUM_EMB 512
#define EDIM 64
#define BATCH 32
#define HW 4096
#define NROWS (BATCH * HW)        // 131072
#define NQ (NROWS * EDIM)         // 8388608

// numpy pairwise_sum for n=64 contiguous fp32 (tiny prep kernel only).
__device__ __forceinline__ float pairwise8_64(const float* v) {
    float r0 = v[0], r1 = v[1], r2 = v[2], r3 = v[3];
    float r4 = v[4], r5 = v[5], r6 = v[6], r7 = v[7];
#pragma unroll
    for (int i = 8; i < 64; i += 8) {
        r0 = __fadd_rn(r0, v[i + 0]);
        r1 = __fadd_rn(r1, v[i + 1]);
        r2 = __fadd_rn(r2, v[i + 2]);
        r3 = __fadd_rn(r3, v[i + 3]);
        r4 = __fadd_rn(r4, v[i + 4]);
        r5 = __fadd_rn(r5, v[i + 5]);
        r6 = __fadd_rn(r6, v[i + 6]);
        r7 = __fadd_rn(r7, v[i + 7]);
    }
    return __fadd_rn(__fadd_rn(__fadd_rn(r0, r1), __fadd_rn(r2, r3)),
                     __fadd_rn(__fadd_rn(r4, r5), __fadd_rn(r6, r7)));
}

// ws_f layout: [0] = loss sum accumulator, [8..8+511] = t2[k] = ||emb_k||^2
__global__ void vq_prep(const float* __restrict__ emb, float* __restrict__ ws_f) {
    int k = blockIdx.x * blockDim.x + threadIdx.x;
    if (k == 0) ws_f[0] = 0.0f;
    if (k < NUM_EMB) {
        const float* e = emb + k * EDIM;
        float sq[EDIM];
#pragma unroll
        for (int c = 0; c < EDIM; ++c) sq[c] = __fmul_rn(e[c], e[c]);
        ws_f[8 + k] = pairwise8_64(sq);
    }
}

// 512 threads: 256 rows x 2 k-halves. Hot loop touches ONLY global memory via
// vector loads (vmcnt, in-order, compiler-pipelineable). No SMEM (round-5
// lgkmcnt-drain bug), no LDS-x, no long-lived register state (rounds 1-4
// spill bug): k-batch=16 accumulators x c-chunk=16 x-values, peak live ~64.
__global__ __launch_bounds__(512, 4) void vq_main(const float* __restrict__ z,
                                                  const float* __restrict__ emb,
                                                  float* __restrict__ out,
                                                  float* __restrict__ ws_f) {
    __shared__ float cb[512];
    __shared__ int   ck[512];

    const int tid  = threadIdx.x;
    const int rl   = tid & 255;           // local row 0..255
    const int half = tid >> 8;            // k-half: 0 -> k<256, 1 -> k>=256
    const int r    = blockIdx.x * 256 + rl;
    const int b    = r >> 12;
    const int hw   = r & 4095;

    const float* zb = z + (size_t)b * (EDIM * HW) + hw;

    // ---- t1 = ||x||^2, numpy pairwise-8: bucket p[c%8], ascending c ----
    float p0, p1, p2, p3, p4, p5, p6, p7;
    {
        float v0 = zb[0 * HW], v1 = zb[1 * HW], v2 = zb[2 * HW], v3 = zb[3 * HW];
        float v4 = zb[4 * HW], v5 = zb[5 * HW], v6 = zb[6 * HW], v7 = zb[7 * HW];
        p0 = __fmul_rn(v0, v0); p1 = __fmul_rn(v1, v1);
        p2 = __fmul_rn(v2, v2); p3 = __fmul_rn(v3, v3);
        p4 = __fmul_rn(v4, v4); p5 = __fmul_rn(v5, v5);
        p6 = __fmul_rn(v6, v6); p7 = __fmul_rn(v7, v7);
    }
#pragma unroll
    for (int m = 1; m < 8; ++m) {
        float v0 = zb[(size_t)(8 * m + 0) * HW], v1 = zb[(size_t)(8 * m + 1) * HW];
        float v2 = zb[(size_t)(8 * m + 2) * HW], v3 = zb[(size_t)(8 * m + 3) * HW];
        float v4 = zb[(size_t)(8 * m + 4) * HW], v5 = zb[(size_t)(8 * m + 5) * HW];
        float v6 = zb[(size_t)(8 * m + 6) * HW], v7 = zb[(size_t)(8 * m + 7) * HW];
        p0 = __fadd_rn(p0, __fmul_rn(v0, v0));
        p1 = __fadd_rn(p1, __fmul_rn(v1, v1));
        p2 = __fadd_rn(p2, __fmul_rn(v2, v2));
        p3 = __fadd_rn(p3, __fmul_rn(v3, v3));
        p4 = __fadd_rn(p4, __fmul_rn(v4, v4));
        p5 = __fadd_rn(p5, __fmul_rn(v5, v5));
        p6 = __fadd_rn(p6, __fmul_rn(v6, v6));
        p7 = __fadd_rn(p7, __fmul_rn(v7, v7));
    }
    const float t1 = __fadd_rn(__fadd_rn(__fadd_rn(p0, p1), __fadd_rn(p2, p3)),
                               __fadd_rn(__fadd_rn(p4, p5), __fadd_rn(p6, p7)));

    const float* __restrict__ t2 = ws_f + 8;
    const float4* __restrict__ e4 = (const float4*)emb;  // 16 float4 per k-row

    const int k0 = half << 8;
    float best = INFINITY;
    int bestk = k0;

    for (int kb = 0; kb < 16; ++kb) {        // 16 k-batches of 16 k's
        const int kbase = k0 + kb * 16;
        float acc[16];
#pragma unroll
        for (int kk = 0; kk < 16; ++kk) acc[kk] = 0.0f;

#pragma unroll
        for (int ch = 0; ch < 4; ++ch) {     // c-chunk of 16 channels
            float xc[16];
#pragma unroll
            for (int i = 0; i < 16; ++i)
                xc[i] = zb[(size_t)(ch * 16 + i) * HW];   // coalesced, L1/L2-hot

#pragma unroll
            for (int kk = 0; kk < 16; ++kk) {
                // e chunk: 4x dwordx4, runtime-uniform address -> L1 broadcast
                const float4* er = e4 + (size_t)(kbase + kk) * 16 + ch * 4;
                float4 ev0 = er[0], ev1 = er[1], ev2 = er[2], ev3 = er[3];
                float a = acc[kk];           // chain: strict ascending c
                a = __fmaf_rn(xc[0],  ev0.x, a);
                a = __fmaf_rn(xc[1],  ev0.y, a);
                a = __fmaf_rn(xc[2],  ev0.z, a);
                a = __fmaf_rn(xc[3],  ev0.w, a);
                a = __fmaf_rn(xc[4],  ev1.x, a);
                a = __fmaf_rn(xc[5],  ev1.y, a);
                a = __fmaf_rn(xc[6],  ev1.z, a);
                a = __fmaf_rn(xc[7],  ev1.w, a);
                a = __fmaf_rn(xc[8],  ev2.x, a);
                a = __fmaf_rn(xc[9],  ev2.y, a);
                a = __fmaf_rn(xc[10], ev2.z, a);
                a = __fmaf_rn(xc[11], ev2.w, a);
                a = __fmaf_rn(xc[12], ev3.x, a);
                a = __fmaf_rn(xc[13], ev3.y, a);
                a = __fmaf_rn(xc[14], ev3.z, a);
                a = __fmaf_rn(xc[15], ev3.w, a);
                acc[kk] = a;
            }
        }

        // d = fl(fl(t1 + t2) - fl(2*p)); strict < keeps lowest index on ties
#pragma unroll
        for (int kk = 0; kk < 16; ++kk) {
            float d = __fsub_rn(__fadd_rn(t1, t2[kbase + kk]),
                                __fmul_rn(2.0f, acc[kk]));
            if (d < best) { best = d; bestk = kbase + kk; }
        }
    }

    // ---- combine the two k-halves (tie -> half 0 = lower k, numpy argmin) ----
    cb[tid] = best;
    ck[tid] = bestk;
    __syncthreads();
    const float bA = cb[rl];
    const float bB = cb[256 + rl];
    const int   kA = ck[rl];
    const int   kB = ck[256 + rl];
    const int   kk = (bB < bA) ? kB : kA;

    // ---- epilogue: each half writes its 32 channels of qst + loss partial ----
    const float* eb = emb + (size_t)kk * EDIM;
    float s = 0.0f;
#pragma unroll
    for (int j = 0; j < 8; ++j) {
        const int c0 = half * 32 + j * 4;
        float xv0 = zb[(size_t)(c0 + 0) * HW];
        float xv1 = zb[(size_t)(c0 + 1) * HW];
        float xv2 = zb[(size_t)(c0 + 2) * HW];
        float xv3 = zb[(size_t)(c0 + 3) * HW];
        float f0 = __fsub_rn(eb[c0 + 0], xv0);
        float f1 = __fsub_rn(eb[c0 + 1], xv1);
        float f2 = __fsub_rn(eb[c0 + 2], xv2);
        float f3 = __fsub_rn(eb[c0 + 3], xv3);
        out[(size_t)(b * EDIM + c0 + 0) * HW + hw] = __fadd_rn(xv0, f0);
        out[(size_t)(b * EDIM + c0 + 1) * HW + hw] = __fadd_rn(xv1, f1);
        out[(size_t)(b * EDIM + c0 + 2) * HW + hw] = __fadd_rn(xv2, f2);
        out[(size_t)(b * EDIM + c0 + 3) * HW + hw] = __fadd_rn(xv3, f3);
        s = __fmaf_rn(f0, f0, s);
        s = __fmaf_rn(f1, f1, s);
        s = __fmaf_rn(f2, f2, s);
        s = __fmaf_rn(f3, f3, s);
    }

    if (half == 0) out[(size_t)NQ + 2 + r] = (float)kk;  // idx as fp32

    // wave-level reduction of loss partial, one atomic per wave
#pragma unroll
    for (int off = 32; off > 0; off >>= 1) s += __shfl_down(s, off);
    if ((threadIdx.x & 63) == 0) atomicAdd(ws_f, s);
}

__global__ void vq_final(const float* __restrict__ ws_f, float* __restrict__ out) {
    float m = ws_f[0] * (1.0f / (float)NQ);   // 2^-23, exact scaling
    out[NQ + 0] = m;
    out[NQ + 1] = m;
}

extern "C" void kernel_launch(void* const* d_in, const int* in_sizes, int n_in,
                              void* d_out, int out_size, void* d_ws, size_t ws_size,
                              hipStream_t stream) {
    const float* z = (const float*)d_in[0];     // [32, 64, 64, 64] fp32
    const float* emb = (const float*)d_in[1];   // [512, 64] fp32
    float* out = (float*)d_out;
    float* ws_f = (float*)d_ws;

    hipLaunchKernelGGL(vq_prep, dim3(1), dim3(512), 0, stream, emb, ws_f);
    hipLaunchKernelGGL(vq_main, dim3(NROWS / 256), dim3(512), 0, stream, z, emb, out, ws_f);
    hipLaunchKernelGGL(vq_final, dim3(1), dim3(1), 0, stream, ws_f, out);
}

// Round 7
// 152.540 us; speedup vs baseline: 3.8751x; 3.8751x over previous
//
#include <hip/hip_runtime.h>
#include <math.h>

#define NUM_EMB 512
#define EDIM 64
#define BATCH 32
#define HW 4096
#define NROWS (BATCH * HW)        // 131072
#define NQ (NROWS * EDIM)         // 8388608

// LDS layout in floats (total 33536 floats = 134144 B)
#define XOFF 0                    // x_t[c][r]   : c*256 + r   (64 x 256)
#define EOFF 16384                // e_t[c][k]   : c*256 + k   (64 x 256, per pass)
#define T2OFF 32768               // t2s[512]
#define T1OFF 33280               // t1s[256]
#define CBOFF 16384               // combine best  [kt][r] (overlays e_t after passes)
#define CKOFF (16384 + 4096)      // combine bestk [kt][r] (int, overlays e_t)
#define SFLOATS 33536

// numpy pairwise_sum for n=64 contiguous fp32 (tiny prep kernel only).
__device__ __forceinline__ float pairwise8_64(const float* v) {
    float r0 = v[0], r1 = v[1], r2 = v[2], r3 = v[3];
    float r4 = v[4], r5 = v[5], r6 = v[6], r7 = v[7];
#pragma unroll
    for (int i = 8; i < 64; i += 8) {
        r0 = __fadd_rn(r0, v[i + 0]);
        r1 = __fadd_rn(r1, v[i + 1]);
        r2 = __fadd_rn(r2, v[i + 2]);
        r3 = __fadd_rn(r3, v[i + 3]);
        r4 = __fadd_rn(r4, v[i + 4]);
        r5 = __fadd_rn(r5, v[i + 5]);
        r6 = __fadd_rn(r6, v[i + 6]);
        r7 = __fadd_rn(r7, v[i + 7]);
    }
    return __fadd_rn(__fadd_rn(__fadd_rn(r0, r1), __fadd_rn(r2, r3)),
                     __fadd_rn(__fadd_rn(r4, r5), __fadd_rn(r6, r7)));
}

// ws_f layout: [0] = loss sum accumulator, [8..8+511] = t2[k] = ||emb_k||^2
__global__ void vq_prep(const float* __restrict__ emb, float* __restrict__ ws_f) {
    int k = blockIdx.x * blockDim.x + threadIdx.x;
    if (k == 0) ws_f[0] = 0.0f;
    if (k < NUM_EMB) {
        const float* e = emb + k * EDIM;
        float sq[EDIM];
#pragma unroll
        for (int c = 0; c < EDIM; ++c) sq[c] = __fmul_rn(e[c], e[c]);
        ws_f[8 + k] = pairwise8_64(sq);
    }
}

// GEMM-style register blocking: 512 threads = 32 row-threads x 16 k-threads.
// Each thread owns an 8-row x 8-k accumulator tile; x and e both stream from
// LDS as ds_read_b128 (single counter class -> fine-grained lgkmcnt, the one
// path proven to pipeline). Per (row,k): acc is ONE chain, c ascending 0..63
// -> bit-identical to the verified rounds. No long-lived x in registers.
__global__ __launch_bounds__(512, 2) void vq_main(const float* __restrict__ z,
                                                  const float* __restrict__ emb,
                                                  float* __restrict__ out,
                                                  float* __restrict__ ws_f) {
    __shared__ float S[SFLOATS];
    const int tid = threadIdx.x;
    const int rt  = tid & 31;       // row-thread: rows rt*8 .. rt*8+7
    const int kt  = tid >> 5;       // k-thread: 16 of them
    const int bb  = blockIdx.x;
    const int b   = bb >> 4;        // batch (16 blocks per batch image)
    const int hwb = (bb & 15) << 8; // block's hw base (256 rows, same batch)

    const float* zb = z + (size_t)b * (EDIM * HW) + hwb;

    // ---- stage x_t[c][r] (transposed) + t2s ----
    {
        const int r = tid & 255, ch = tid >> 8;
#pragma unroll
        for (int j = 0; j < 32; ++j) {
            const int c = ch * 32 + j;
            S[XOFF + c * 256 + r] = zb[(size_t)c * HW + r];  // coalesced lanes->r
        }
    }
    S[T2OFF + tid] = ws_f[8 + tid];
    __syncthreads();

    // ---- t1 per row: numpy pairwise-8, ascending c, from x_t ----
    if (tid < 256) {
        const float* xr = &S[XOFF + tid];   // stride 256 per c
        float q0 = __fmul_rn(xr[0 * 256], xr[0 * 256]);
        float q1 = __fmul_rn(xr[1 * 256], xr[1 * 256]);
        float q2 = __fmul_rn(xr[2 * 256], xr[2 * 256]);
        float q3 = __fmul_rn(xr[3 * 256], xr[3 * 256]);
        float q4 = __fmul_rn(xr[4 * 256], xr[4 * 256]);
        float q5 = __fmul_rn(xr[5 * 256], xr[5 * 256]);
        float q6 = __fmul_rn(xr[6 * 256], xr[6 * 256]);
        float q7 = __fmul_rn(xr[7 * 256], xr[7 * 256]);
#pragma unroll
        for (int m = 1; m < 8; ++m) {
            float v0 = xr[(8 * m + 0) * 256], v1 = xr[(8 * m + 1) * 256];
            float v2 = xr[(8 * m + 2) * 256], v3 = xr[(8 * m + 3) * 256];
            float v4 = xr[(8 * m + 4) * 256], v5 = xr[(8 * m + 5) * 256];
            float v6 = xr[(8 * m + 6) * 256], v7 = xr[(8 * m + 7) * 256];
            q0 = __fadd_rn(q0, __fmul_rn(v0, v0));
            q1 = __fadd_rn(q1, __fmul_rn(v1, v1));
            q2 = __fadd_rn(q2, __fmul_rn(v2, v2));
            q3 = __fadd_rn(q3, __fmul_rn(v3, v3));
            q4 = __fadd_rn(q4, __fmul_rn(v4, v4));
            q5 = __fadd_rn(q5, __fmul_rn(v5, v5));
            q6 = __fadd_rn(q6, __fmul_rn(v6, v6));
            q7 = __fadd_rn(q7, __fmul_rn(v7, v7));
        }
        S[T1OFF + tid] = __fadd_rn(__fadd_rn(__fadd_rn(q0, q1), __fadd_rn(q2, q3)),
                                   __fadd_rn(__fadd_rn(q4, q5), __fadd_rn(q6, q7)));
    }
    __syncthreads();

    float t1r[8];
#pragma unroll
    for (int i = 0; i < 8; ++i) t1r[i] = S[T1OFF + rt * 8 + i];

    float best[8];
    int   bki[8];
#pragma unroll
    for (int i = 0; i < 8; ++i) { best[i] = INFINITY; bki[i] = 0; }

    // ---- two passes over the codebook (256 k each) ----
    for (int p = 0; p < 2; ++p) {
        // stage e_t[c][k] (transposed); lanes write consecutive k -> no conflict
        {
            const int k = tid & 255, ch = tid >> 8;
            const float4* er = (const float4*)(emb + (size_t)(p * 256 + k) * EDIM);
#pragma unroll
            for (int j = 0; j < 8; ++j) {
                const float4 v = er[ch * 8 + j];
                const int c = ch * 32 + j * 4;
                S[EOFF + (c + 0) * 256 + k] = v.x;
                S[EOFF + (c + 1) * 256 + k] = v.y;
                S[EOFF + (c + 2) * 256 + k] = v.z;
                S[EOFF + (c + 3) * 256 + k] = v.w;
            }
        }
        __syncthreads();

#pragma unroll
        for (int blk = 0; blk < 2; ++blk) {
            const int kb = kt * 16 + blk * 8;   // local k base (within pass)
            float acc[8][8];
#pragma unroll
            for (int i = 0; i < 8; ++i)
#pragma unroll
                for (int j = 0; j < 8; ++j) acc[i][j] = 0.0f;

#pragma unroll 4
            for (int c = 0; c < 64; ++c) {
                const float4 xa = *(const float4*)&S[XOFF + c * 256 + rt * 8];
                const float4 xb = *(const float4*)&S[XOFF + c * 256 + rt * 8 + 4];
                const float4 ea = *(const float4*)&S[EOFF + c * 256 + kb];
                const float4 eb = *(const float4*)&S[EOFF + c * 256 + kb + 4];
#define ROW(i, xv) \
                acc[i][0] = __fmaf_rn(xv, ea.x, acc[i][0]); \
                acc[i][1] = __fmaf_rn(xv, ea.y, acc[i][1]); \
                acc[i][2] = __fmaf_rn(xv, ea.z, acc[i][2]); \
                acc[i][3] = __fmaf_rn(xv, ea.w, acc[i][3]); \
                acc[i][4] = __fmaf_rn(xv, eb.x, acc[i][4]); \
                acc[i][5] = __fmaf_rn(xv, eb.y, acc[i][5]); \
                acc[i][6] = __fmaf_rn(xv, eb.z, acc[i][6]); \
                acc[i][7] = __fmaf_rn(xv, eb.w, acc[i][7]);
                ROW(0, xa.x) ROW(1, xa.y) ROW(2, xa.z) ROW(3, xa.w)
                ROW(4, xb.x) ROW(5, xb.y) ROW(6, xb.z) ROW(7, xb.w)
#undef ROW
            }

            // finish: d = fl(fl(t1 + t2) - fl(2*p)); in-thread k ascending
#pragma unroll
            for (int j = 0; j < 8; ++j) {
                const int kg = p * 256 + kb + j;
                const float t2k = S[T2OFF + kg];
#pragma unroll
                for (int i = 0; i < 8; ++i) {
                    float d = __fsub_rn(__fadd_rn(t1r[i], t2k),
                                        __fmul_rn(2.0f, acc[i][j]));
                    if (d < best[i]) { best[i] = d; bki[i] = kg; }
                }
            }
        }
        __syncthreads();   // e_t consumed; safe to restage / overlay
    }

    // ---- combine across the 16 k-threads (overlay on e_t region) ----
#pragma unroll
    for (int i = 0; i < 8; ++i) {
        S[CBOFF + kt * 256 + rt * 8 + i] = best[i];
        ((int*)S)[CKOFF + kt * 256 + rt * 8 + i] = bki[i];
    }
    __syncthreads();

    if (tid < 256) {
        const int row = tid;
        float B = INFINITY;
        int   K = 0;
        // lexicographic (d, k) min == numpy argmin lowest-index tie-break,
        // required because the kt partition interleaves k ranges.
#pragma unroll
        for (int q = 0; q < 16; ++q) {
            const float bq = S[CBOFF + q * 256 + row];
            const int   kq = ((int*)S)[CKOFF + q * 256 + row];
            if (bq < B || (bq == B && kq < K)) { B = bq; K = kq; }
        }

        // epilogue: qst = fl(x + fl(q - x)), loss partial, idx
        const float* eb = emb + (size_t)K * EDIM;
        const float* xc = &S[XOFF + row];
        float s = 0.0f;
#pragma unroll
        for (int c = 0; c < 64; ++c) {
            const float x = xc[c * 256];
            const float f = __fsub_rn(eb[c], x);
            out[((size_t)b * EDIM + c) * HW + hwb + row] = __fadd_rn(x, f);
            s = __fmaf_rn(f, f, s);
        }
        out[(size_t)NQ + 2 + bb * 256 + row] = (float)K;

#pragma unroll
        for (int off = 32; off > 0; off >>= 1) s += __shfl_down(s, off);
        if ((tid & 63) == 0) atomicAdd(ws_f, s);
    }
}

__global__ void vq_final(const float* __restrict__ ws_f, float* __restrict__ out) {
    float m = ws_f[0] * (1.0f / (float)NQ);   // 2^-23, exact scaling
    out[NQ + 0] = m;
    out[NQ + 1] = m;
}

extern "C" void kernel_launch(void* const* d_in, const int* in_sizes, int n_in,
                              void* d_out, int out_size, void* d_ws, size_t ws_size,
                              hipStream_t stream) {
    const float* z = (const float*)d_in[0];     // [32, 64, 64, 64] fp32
    const float* emb = (const float*)d_in[1];   // [512, 64] fp32
    float* out = (float*)d_out;
    float* ws_f = (float*)d_ws;

    hipLaunchKernelGGL(vq_prep, dim3(1), dim3(512), 0, stream, emb, ws_f);
    hipLaunchKernelGGL(vq_main, dim3(NROWS / 256), dim3(512), 0, stream, z, emb, out, ws_f);
    hipLaunchKernelGGL(vq_final, dim3(1), dim3(1), 0, stream, ws_f, out);
}

// Round 8
// 152.150 us; speedup vs baseline: 3.8850x; 1.0026x over previous
//
#include <hip/hip_runtime.h>
#include <math.h>

#define NUM_EMB 512
#define EDIM 64
#define BATCH 32
#define HW 4096
#define NROWS (BATCH * HW)        // 131072
#define NQ (NROWS * EDIM)         // 8388608

// LDS layout in floats (total 33536 floats = 134144 B)
#define XOFF 0                    // x_t[c][r]   : c*256 + r   (64 x 256)
#define EOFF 16384                // e_t[c][k]   : c*256 + k   (64 x 256, per pass)
#define T2OFF 32768               // t2s[512]
#define T1OFF 33280               // t1s[256]
#define CBOFF 16384               // combine best  [kt][r] (overlays e_t after passes)
#define CKOFF (16384 + 4096)      // combine bestk [kt][r] (int, overlays e_t)
#define SFLOATS 33536

// numpy pairwise_sum for n=64 contiguous fp32 (tiny prep kernel only).
__device__ __forceinline__ float pairwise8_64(const float* v) {
    float r0 = v[0], r1 = v[1], r2 = v[2], r3 = v[3];
    float r4 = v[4], r5 = v[5], r6 = v[6], r7 = v[7];
#pragma unroll
    for (int i = 8; i < 64; i += 8) {
        r0 = __fadd_rn(r0, v[i + 0]);
        r1 = __fadd_rn(r1, v[i + 1]);
        r2 = __fadd_rn(r2, v[i + 2]);
        r3 = __fadd_rn(r3, v[i + 3]);
        r4 = __fadd_rn(r4, v[i + 4]);
        r5 = __fadd_rn(r5, v[i + 5]);
        r6 = __fadd_rn(r6, v[i + 6]);
        r7 = __fadd_rn(r7, v[i + 7]);
    }
    return __fadd_rn(__fadd_rn(__fadd_rn(r0, r1), __fadd_rn(r2, r3)),
                     __fadd_rn(__fadd_rn(r4, r5), __fadd_rn(r6, r7)));
}

// ws_f layout: [0] = loss sum accumulator, [8..8+511] = t2[k] = ||emb_k||^2
__global__ void vq_prep(const float* __restrict__ emb, float* __restrict__ ws_f) {
    int k = blockIdx.x * blockDim.x + threadIdx.x;
    if (k == 0) ws_f[0] = 0.0f;
    if (k < NUM_EMB) {
        const float* e = emb + k * EDIM;
        float sq[EDIM];
#pragma unroll
        for (int c = 0; c < EDIM; ++c) sq[c] = __fmul_rn(e[c], e[c]);
        ws_f[8 + k] = pairwise8_64(sq);
    }
}

// GEMM-style register blocking: 512 threads = 32 row-threads x 16 k-threads.
// Each thread owns 8 rows x 8 k. ROW MAPPING (round-8 fix): thread rt owns
// rows {rt*4..rt*4+3} and {128+rt*4..128+rt*4+3} so the two x ds_read_b128's
// have lanes reading CONSECUTIVE float4s (byte 16*l) -> zero bank conflicts
// (round 7: rt*8 stride-32B pattern cost 8.55M conflict cycles).
__global__ __launch_bounds__(512, 2) void vq_main(const float* __restrict__ z,
                                                  const float* __restrict__ emb,
                                                  float* __restrict__ out,
                                                  float* __restrict__ ws_f) {
    __shared__ float S[SFLOATS];
    const int tid = threadIdx.x;
    const int rt  = tid & 31;       // row-thread
    const int kt  = tid >> 5;       // k-thread: 16 of them
    const int row0 = rt * 4;        // rows row0+i and 128+row0+i
    const int bb  = blockIdx.x;
    const int b   = bb >> 4;        // batch (16 blocks per batch image)
    const int hwb = (bb & 15) << 8; // block's hw base (256 rows, same batch)

    const float* zb = z + (size_t)b * (EDIM * HW) + hwb;

    // ---- stage x_t[c][r] (transposed) + t2s ----
    {
        const int r = tid & 255, ch = tid >> 8;
#pragma unroll
        for (int j = 0; j < 32; ++j) {
            const int c = ch * 32 + j;
            S[XOFF + c * 256 + r] = zb[(size_t)c * HW + r];  // coalesced lanes->r
        }
    }
    S[T2OFF + tid] = ws_f[8 + tid];
    __syncthreads();

    // ---- t1 per row: numpy pairwise-8, ascending c, from x_t ----
    if (tid < 256) {
        const float* xr = &S[XOFF + tid];   // stride 256 per c
        float q0 = __fmul_rn(xr[0 * 256], xr[0 * 256]);
        float q1 = __fmul_rn(xr[1 * 256], xr[1 * 256]);
        float q2 = __fmul_rn(xr[2 * 256], xr[2 * 256]);
        float q3 = __fmul_rn(xr[3 * 256], xr[3 * 256]);
        float q4 = __fmul_rn(xr[4 * 256], xr[4 * 256]);
        float q5 = __fmul_rn(xr[5 * 256], xr[5 * 256]);
        float q6 = __fmul_rn(xr[6 * 256], xr[6 * 256]);
        float q7 = __fmul_rn(xr[7 * 256], xr[7 * 256]);
#pragma unroll
        for (int m = 1; m < 8; ++m) {
            float v0 = xr[(8 * m + 0) * 256], v1 = xr[(8 * m + 1) * 256];
            float v2 = xr[(8 * m + 2) * 256], v3 = xr[(8 * m + 3) * 256];
            float v4 = xr[(8 * m + 4) * 256], v5 = xr[(8 * m + 5) * 256];
            float v6 = xr[(8 * m + 6) * 256], v7 = xr[(8 * m + 7) * 256];
            q0 = __fadd_rn(q0, __fmul_rn(v0, v0));
            q1 = __fadd_rn(q1, __fmul_rn(v1, v1));
            q2 = __fadd_rn(q2, __fmul_rn(v2, v2));
            q3 = __fadd_rn(q3, __fmul_rn(v3, v3));
            q4 = __fadd_rn(q4, __fmul_rn(v4, v4));
            q5 = __fadd_rn(q5, __fmul_rn(v5, v5));
            q6 = __fadd_rn(q6, __fmul_rn(v6, v6));
            q7 = __fadd_rn(q7, __fmul_rn(v7, v7));
        }
        S[T1OFF + tid] = __fadd_rn(__fadd_rn(__fadd_rn(q0, q1), __fadd_rn(q2, q3)),
                                   __fadd_rn(__fadd_rn(q4, q5), __fadd_rn(q6, q7)));
    }
    __syncthreads();

    float t1r[8];
#pragma unroll
    for (int i = 0; i < 4; ++i) t1r[i] = S[T1OFF + row0 + i];
#pragma unroll
    for (int i = 4; i < 8; ++i) t1r[i] = S[T1OFF + 128 + row0 + (i - 4)];

    float best[8];
    int   bki[8];
#pragma unroll
    for (int i = 0; i < 8; ++i) { best[i] = INFINITY; bki[i] = 0; }

    // ---- two passes over the codebook (256 k each) ----
    for (int p = 0; p < 2; ++p) {
        // stage e_t[c][k] (transposed); lanes write consecutive k -> no conflict
        {
            const int k = tid & 255, ch = tid >> 8;
            const float4* er = (const float4*)(emb + (size_t)(p * 256 + k) * EDIM);
#pragma unroll
            for (int j = 0; j < 8; ++j) {
                const float4 v = er[ch * 8 + j];
                const int c = ch * 32 + j * 4;
                S[EOFF + (c + 0) * 256 + k] = v.x;
                S[EOFF + (c + 1) * 256 + k] = v.y;
                S[EOFF + (c + 2) * 256 + k] = v.z;
                S[EOFF + (c + 3) * 256 + k] = v.w;
            }
        }
        __syncthreads();

#pragma unroll
        for (int blk = 0; blk < 2; ++blk) {
            const int kb = kt * 16 + blk * 8;   // local k base (within pass)
            float acc[8][8];
#pragma unroll
            for (int i = 0; i < 8; ++i)
#pragma unroll
                for (int j = 0; j < 8; ++j) acc[i][j] = 0.0f;

#pragma unroll 4
            for (int c = 0; c < 64; ++c) {
                // lanes -> consecutive float4s (byte 16*lane): conflict-free
                const float4 xa = *(const float4*)&S[XOFF + c * 256 + row0];
                const float4 xb = *(const float4*)&S[XOFF + c * 256 + 128 + row0];
                const float4 ea = *(const float4*)&S[EOFF + c * 256 + kb];
                const float4 eb = *(const float4*)&S[EOFF + c * 256 + kb + 4];
#define ROW(i, xv) \
                acc[i][0] = __fmaf_rn(xv, ea.x, acc[i][0]); \
                acc[i][1] = __fmaf_rn(xv, ea.y, acc[i][1]); \
                acc[i][2] = __fmaf_rn(xv, ea.z, acc[i][2]); \
                acc[i][3] = __fmaf_rn(xv, ea.w, acc[i][3]); \
                acc[i][4] = __fmaf_rn(xv, eb.x, acc[i][4]); \
                acc[i][5] = __fmaf_rn(xv, eb.y, acc[i][5]); \
                acc[i][6] = __fmaf_rn(xv, eb.z, acc[i][6]); \
                acc[i][7] = __fmaf_rn(xv, eb.w, acc[i][7]);
                ROW(0, xa.x) ROW(1, xa.y) ROW(2, xa.z) ROW(3, xa.w)
                ROW(4, xb.x) ROW(5, xb.y) ROW(6, xb.z) ROW(7, xb.w)
#undef ROW
            }

            // finish: d = fl(fl(t1 + t2) - fl(2*p)); in-thread k ascending
#pragma unroll
            for (int j = 0; j < 8; ++j) {
                const int kg = p * 256 + kb + j;
                const float t2k = S[T2OFF + kg];
#pragma unroll
                for (int i = 0; i < 8; ++i) {
                    float d = __fsub_rn(__fadd_rn(t1r[i], t2k),
                                        __fmul_rn(2.0f, acc[i][j]));
                    if (d < best[i]) { best[i] = d; bki[i] = kg; }
                }
            }
        }
        __syncthreads();   // e_t consumed; safe to restage / overlay
    }

    // ---- combine across the 16 k-threads (overlay on e_t region) ----
#pragma unroll
    for (int i = 0; i < 4; ++i) {
        S[CBOFF + kt * 256 + row0 + i] = best[i];
        ((int*)S)[CKOFF + kt * 256 + row0 + i] = bki[i];
    }
#pragma unroll
    for (int i = 4; i < 8; ++i) {
        S[CBOFF + kt * 256 + 128 + row0 + (i - 4)] = best[i];
        ((int*)S)[CKOFF + kt * 256 + 128 + row0 + (i - 4)] = bki[i];
    }
    __syncthreads();

    if (tid < 256) {
        const int row = tid;
        float B = INFINITY;
        int   K = 0;
        // lexicographic (d, k) min == numpy argmin lowest-index tie-break,
        // required because the kt partition interleaves k ranges.
#pragma unroll
        for (int q = 0; q < 16; ++q) {
            const float bq = S[CBOFF + q * 256 + row];
            const int   kq = ((int*)S)[CKOFF + q * 256 + row];
            if (bq < B || (bq == B && kq < K)) { B = bq; K = kq; }
        }

        // epilogue: qst = fl(x + fl(q - x)), loss partial, idx
        const float* eb = emb + (size_t)K * EDIM;
        const float* xc = &S[XOFF + row];
        float s = 0.0f;
#pragma unroll
        for (int c = 0; c < 64; ++c) {
            const float x = xc[c * 256];
            const float f = __fsub_rn(eb[c], x);
            out[((size_t)b * EDIM + c) * HW + hwb + row] = __fadd_rn(x, f);
            s = __fmaf_rn(f, f, s);
        }
        out[(size_t)NQ + 2 + bb * 256 + row] = (float)K;

#pragma unroll
        for (int off = 32; off > 0; off >>= 1) s += __shfl_down(s, off);
        if ((tid & 63) == 0) atomicAdd(ws_f, s);
    }
}

__global__ void vq_final(const float* __restrict__ ws_f, float* __restrict__ out) {
    float m = ws_f[0] * (1.0f / (float)NQ);   // 2^-23, exact scaling
    out[NQ + 0] = m;
    out[NQ + 1] = m;
}

extern "C" void kernel_launch(void* const* d_in, const int* in_sizes, int n_in,
                              void* d_out, int out_size, void* d_ws, size_t ws_size,
                              hipStream_t stream) {
    const float* z = (const float*)d_in[0];     // [32, 64, 64, 64] fp32
    const float* emb = (const float*)d_in[1];   // [512, 64] fp32
    float* out = (float*)d_out;
    float* ws_f = (float*)d_ws;

    hipLaunchKernelGGL(vq_prep, dim3(1), dim3(512), 0, stream, emb, ws_f);
    hipLaunchKernelGGL(vq_main, dim3(NROWS / 256), dim3(512), 0, stream, z, emb, out, ws_f);
    hipLaunchKernelGGL(vq_final, dim3(1), dim3(1), 0, stream, ws_f, out);
}

// Round 9
// 147.040 us; speedup vs baseline: 4.0200x; 1.0347x over previous
//
#include <hip/hip_runtime.h>
#include <math.h>

#define NUM_EMB 512
#define EDIM 64
#define BATCH 32
#define HW 4096
#define NROWS (BATCH * HW)        // 131072
#define NQ (NROWS * EDIM)         // 8388608

// LDS layout in floats (total 33536 floats = 134144 B)
#define XOFF 0                    // x_t[c][r]   : c*256 + r   (64 x 256)
#define EOFF 16384                // e_t[c][k]   : c*256 + k   (64 x 256, per pass)
#define T2OFF 32768               // t2s[512]
#define T1OFF 33280               // t1s[256]
#define CBOFF 16384               // combine best  [kt][r] (overlays e_t after passes)
#define CKOFF (16384 + 4096)      // combine bestk [kt][r] (int, overlays e_t)
#define SFLOATS 33536

// numpy pairwise_sum for n=64 contiguous fp32 (tiny prep kernel only).
__device__ __forceinline__ float pairwise8_64(const float* v) {
    float r0 = v[0], r1 = v[1], r2 = v[2], r3 = v[3];
    float r4 = v[4], r5 = v[5], r6 = v[6], r7 = v[7];
#pragma unroll
    for (int i = 8; i < 64; i += 8) {
        r0 = __fadd_rn(r0, v[i + 0]);
        r1 = __fadd_rn(r1, v[i + 1]);
        r2 = __fadd_rn(r2, v[i + 2]);
        r3 = __fadd_rn(r3, v[i + 3]);
        r4 = __fadd_rn(r4, v[i + 4]);
        r5 = __fadd_rn(r5, v[i + 5]);
        r6 = __fadd_rn(r6, v[i + 6]);
        r7 = __fadd_rn(r7, v[i + 7]);
    }
    return __fadd_rn(__fadd_rn(__fadd_rn(r0, r1), __fadd_rn(r2, r3)),
                     __fadd_rn(__fadd_rn(r4, r5), __fadd_rn(r6, r7)));
}

// ws_f layout: [0] = loss sum accumulator, [8..8+511] = t2[k] = ||emb_k||^2
__global__ void vq_prep(const float* __restrict__ emb, float* __restrict__ ws_f) {
    int k = blockIdx.x * blockDim.x + threadIdx.x;
    if (k == 0) ws_f[0] = 0.0f;
    if (k < NUM_EMB) {
        const float* e = emb + k * EDIM;
        float sq[EDIM];
#pragma unroll
        for (int c = 0; c < EDIM; ++c) sq[c] = __fmul_rn(e[c], e[c]);
        ws_f[8 + k] = pairwise8_64(sq);
    }
}

// GEMM-style register blocking: 512 threads = 32 row-threads x 16 k-threads.
// Round-9 change: k-tile widened 8 -> 16 (acc[8][16]) so each c-iteration is
// 6 ds_read_b128 -> 128 FMA (round 8: 4 reads -> 64 FMA). Cuts per-thread
// LDS reads 1024 -> 768; the per-CU LDS pipe (~82 us in round 8, the real
// floor) drops at/below the 54.6 us FMA-issue floor. Row mapping keeps the
// round-8 conflict-free pattern (rows rt*4 and 128+rt*4).
__global__ __launch_bounds__(512, 2) void vq_main(const float* __restrict__ z,
                                                  const float* __restrict__ emb,
                                                  float* __restrict__ out,
                                                  float* __restrict__ ws_f) {
    __shared__ float S[SFLOATS];
    const int tid = threadIdx.x;
    const int rt  = tid & 31;       // row-thread
    const int kt  = tid >> 5;       // k-thread: 16 of them
    const int row0 = rt * 4;        // rows row0+i and 128+row0+i
    const int bb  = blockIdx.x;
    const int b   = bb >> 4;        // batch (16 blocks per batch image)
    const int hwb = (bb & 15) << 8; // block's hw base (256 rows, same batch)

    const float* zb = z + (size_t)b * (EDIM * HW) + hwb;

    // ---- stage x_t[c][r] (transposed) + t2s ----
    {
        const int r = tid & 255, ch = tid >> 8;
#pragma unroll
        for (int j = 0; j < 32; ++j) {
            const int c = ch * 32 + j;
            S[XOFF + c * 256 + r] = zb[(size_t)c * HW + r];  // coalesced lanes->r
        }
    }
    S[T2OFF + tid] = ws_f[8 + tid];
    __syncthreads();

    // ---- t1 per row: numpy pairwise-8, ascending c, from x_t ----
    if (tid < 256) {
        const float* xr = &S[XOFF + tid];   // stride 256 per c
        float q0 = __fmul_rn(xr[0 * 256], xr[0 * 256]);
        float q1 = __fmul_rn(xr[1 * 256], xr[1 * 256]);
        float q2 = __fmul_rn(xr[2 * 256], xr[2 * 256]);
        float q3 = __fmul_rn(xr[3 * 256], xr[3 * 256]);
        float q4 = __fmul_rn(xr[4 * 256], xr[4 * 256]);
        float q5 = __fmul_rn(xr[5 * 256], xr[5 * 256]);
        float q6 = __fmul_rn(xr[6 * 256], xr[6 * 256]);
        float q7 = __fmul_rn(xr[7 * 256], xr[7 * 256]);
#pragma unroll
        for (int m = 1; m < 8; ++m) {
            float v0 = xr[(8 * m + 0) * 256], v1 = xr[(8 * m + 1) * 256];
            float v2 = xr[(8 * m + 2) * 256], v3 = xr[(8 * m + 3) * 256];
            float v4 = xr[(8 * m + 4) * 256], v5 = xr[(8 * m + 5) * 256];
            float v6 = xr[(8 * m + 6) * 256], v7 = xr[(8 * m + 7) * 256];
            q0 = __fadd_rn(q0, __fmul_rn(v0, v0));
            q1 = __fadd_rn(q1, __fmul_rn(v1, v1));
            q2 = __fadd_rn(q2, __fmul_rn(v2, v2));
            q3 = __fadd_rn(q3, __fmul_rn(v3, v3));
            q4 = __fadd_rn(q4, __fmul_rn(v4, v4));
            q5 = __fadd_rn(q5, __fmul_rn(v5, v5));
            q6 = __fadd_rn(q6, __fmul_rn(v6, v6));
            q7 = __fadd_rn(q7, __fmul_rn(v7, v7));
        }
        S[T1OFF + tid] = __fadd_rn(__fadd_rn(__fadd_rn(q0, q1), __fadd_rn(q2, q3)),
                                   __fadd_rn(__fadd_rn(q4, q5), __fadd_rn(q6, q7)));
    }
    __syncthreads();

    float t1r[8];
#pragma unroll
    for (int i = 0; i < 4; ++i) t1r[i] = S[T1OFF + row0 + i];
#pragma unroll
    for (int i = 4; i < 8; ++i) t1r[i] = S[T1OFF + 128 + row0 + (i - 4)];

    float best[8];
    int   bki[8];
#pragma unroll
    for (int i = 0; i < 8; ++i) { best[i] = INFINITY; bki[i] = 0; }

    // ---- two passes over the codebook (256 k each) ----
    for (int p = 0; p < 2; ++p) {
        // stage e_t[c][k] (transposed); lanes write consecutive k -> no conflict
        {
            const int k = tid & 255, ch = tid >> 8;
            const float4* er = (const float4*)(emb + (size_t)(p * 256 + k) * EDIM);
#pragma unroll
            for (int j = 0; j < 8; ++j) {
                const float4 v = er[ch * 8 + j];
                const int c = ch * 32 + j * 4;
                S[EOFF + (c + 0) * 256 + k] = v.x;
                S[EOFF + (c + 1) * 256 + k] = v.y;
                S[EOFF + (c + 2) * 256 + k] = v.z;
                S[EOFF + (c + 3) * 256 + k] = v.w;
            }
        }
        __syncthreads();

        {
            const int kb = kt * 16;             // 16 contiguous k per thread
            float acc[8][16];
#pragma unroll
            for (int i = 0; i < 8; ++i)
#pragma unroll
                for (int j = 0; j < 16; ++j) acc[i][j] = 0.0f;

#pragma unroll 2
            for (int c = 0; c < 64; ++c) {
                // lanes -> consecutive float4s (byte 16*lane): conflict-free
                const float4 xa = *(const float4*)&S[XOFF + c * 256 + row0];
                const float4 xb = *(const float4*)&S[XOFF + c * 256 + 128 + row0];
                // half-wave-uniform addresses -> LDS broadcast
                const float4 e0 = *(const float4*)&S[EOFF + c * 256 + kb];
                const float4 e1 = *(const float4*)&S[EOFF + c * 256 + kb + 4];
                const float4 e2 = *(const float4*)&S[EOFF + c * 256 + kb + 8];
                const float4 e3 = *(const float4*)&S[EOFF + c * 256 + kb + 12];
#define ROW(i, xv) \
                acc[i][0]  = __fmaf_rn(xv, e0.x, acc[i][0]);  \
                acc[i][1]  = __fmaf_rn(xv, e0.y, acc[i][1]);  \
                acc[i][2]  = __fmaf_rn(xv, e0.z, acc[i][2]);  \
                acc[i][3]  = __fmaf_rn(xv, e0.w, acc[i][3]);  \
                acc[i][4]  = __fmaf_rn(xv, e1.x, acc[i][4]);  \
                acc[i][5]  = __fmaf_rn(xv, e1.y, acc[i][5]);  \
                acc[i][6]  = __fmaf_rn(xv, e1.z, acc[i][6]);  \
                acc[i][7]  = __fmaf_rn(xv, e1.w, acc[i][7]);  \
                acc[i][8]  = __fmaf_rn(xv, e2.x, acc[i][8]);  \
                acc[i][9]  = __fmaf_rn(xv, e2.y, acc[i][9]);  \
                acc[i][10] = __fmaf_rn(xv, e2.z, acc[i][10]); \
                acc[i][11] = __fmaf_rn(xv, e2.w, acc[i][11]); \
                acc[i][12] = __fmaf_rn(xv, e3.x, acc[i][12]); \
                acc[i][13] = __fmaf_rn(xv, e3.y, acc[i][13]); \
                acc[i][14] = __fmaf_rn(xv, e3.z, acc[i][14]); \
                acc[i][15] = __fmaf_rn(xv, e3.w, acc[i][15]);
                ROW(0, xa.x) ROW(1, xa.y) ROW(2, xa.z) ROW(3, xa.w)
                ROW(4, xb.x) ROW(5, xb.y) ROW(6, xb.z) ROW(7, xb.w)
#undef ROW
            }

            // finish: d = fl(fl(t1 + t2) - fl(2*p)); in-thread k ascending
#pragma unroll
            for (int j = 0; j < 16; ++j) {
                const int kg = p * 256 + kb + j;
                const float t2k = S[T2OFF + kg];
#pragma unroll
                for (int i = 0; i < 8; ++i) {
                    float d = __fsub_rn(__fadd_rn(t1r[i], t2k),
                                        __fmul_rn(2.0f, acc[i][j]));
                    if (d < best[i]) { best[i] = d; bki[i] = kg; }
                }
            }
        }
        __syncthreads();   // e_t consumed; safe to restage / overlay
    }

    // ---- combine across the 16 k-threads (overlay on e_t region) ----
#pragma unroll
    for (int i = 0; i < 4; ++i) {
        S[CBOFF + kt * 256 + row0 + i] = best[i];
        ((int*)S)[CKOFF + kt * 256 + row0 + i] = bki[i];
    }
#pragma unroll
    for (int i = 4; i < 8; ++i) {
        S[CBOFF + kt * 256 + 128 + row0 + (i - 4)] = best[i];
        ((int*)S)[CKOFF + kt * 256 + 128 + row0 + (i - 4)] = bki[i];
    }
    __syncthreads();

    if (tid < 256) {
        const int row = tid;
        float B = INFINITY;
        int   K = 0;
        // lexicographic (d, k) min == numpy argmin lowest-index tie-break,
        // required because the kt partition interleaves k ranges.
#pragma unroll
        for (int q = 0; q < 16; ++q) {
            const float bq = S[CBOFF + q * 256 + row];
            const int   kq = ((int*)S)[CKOFF + q * 256 + row];
            if (bq < B || (bq == B && kq < K)) { B = bq; K = kq; }
        }

        // epilogue: qst = fl(x + fl(q - x)), loss partial, idx
        const float* eb = emb + (size_t)K * EDIM;
        const float* xc = &S[XOFF + row];
        float s = 0.0f;
#pragma unroll
        for (int c = 0; c < 64; ++c) {
            const float x = xc[c * 256];
            const float f = __fsub_rn(eb[c], x);
            out[((size_t)b * EDIM + c) * HW + hwb + row] = __fadd_rn(x, f);
            s = __fmaf_rn(f, f, s);
        }
        out[(size_t)NQ + 2 + bb * 256 + row] = (float)K;

#pragma unroll
        for (int off = 32; off > 0; off >>= 1) s += __shfl_down(s, off);
        if ((tid & 63) == 0) atomicAdd(ws_f, s);
    }
}

__global__ void vq_final(const float* __restrict__ ws_f, float* __restrict__ out) {
    float m = ws_f[0] * (1.0f / (float)NQ);   // 2^-23, exact scaling
    out[NQ + 0] = m;
    out[NQ + 1] = m;
}

extern "C" void kernel_launch(void* const* d_in, const int* in_sizes, int n_in,
                              void* d_out, int out_size, void* d_ws, size_t ws_size,
                              hipStream_t stream) {
    const float* z = (const float*)d_in[0];     // [32, 64, 64, 64] fp32
    const float* emb = (const float*)d_in[1];   // [512, 64] fp32
    float* out = (float*)d_out;
    float* ws_f = (float*)d_ws;

    hipLaunchKernelGGL(vq_prep, dim3(1), dim3(512), 0, stream, emb, ws_f);
    hipLaunchKernelGGL(vq_main, dim3(NROWS / 256), dim3(512), 0, stream, z, emb, out, ws_f);
    hipLaunchKernelGGL(vq_final, dim3(1), dim3(1), 0, stream, ws_f, out);
}